// Round 12
// baseline (193.842 us; speedup 1.0000x reference)
//
#include <hip/hip_runtime.h>
#include <stdint.h>

#define SEQ 2048
#define DIM 1024
#define NB 4
#define MTOT (NB*SEQ)
#define QKVN (3*DIM)

typedef __attribute__((ext_vector_type(8))) short short8;
typedef __attribute__((ext_vector_type(4))) float f32x4;

__device__ __forceinline__ unsigned short f2b(float f) {
    union { float f; unsigned int u; } v; v.f = f;
    return (unsigned short)((v.u + 0x7FFFu + ((v.u >> 16) & 1u)) >> 16);
}

__device__ __forceinline__ void gload_lds16(const unsigned short* g, unsigned short* l) {
    __builtin_amdgcn_global_load_lds(
        (const __attribute__((address_space(1))) void*)g,
        (__attribute__((address_space(3))) void*)l, 16, 0, 0);
}

// inline-asm LDS read: invisible to backend waitcnt insertion; dependency on the
// LDS-DMA is managed ONLY by our counted vmcnt/lgkmcnt ledger.
__device__ __forceinline__ short8 ds128(unsigned addr) {
    short8 r;
    asm volatile("ds_read_b128 %0, %1" : "=v"(r) : "v"(addr));
    return r;
}

#define FENCE_BARRIER do { asm volatile("" ::: "memory"); \
    __builtin_amdgcn_s_barrier(); asm volatile("" ::: "memory"); } while (0)

__device__ __forceinline__ int xcd_swz(int bid, int nwg) {
    if (nwg & 7) return bid;
    return (bid & 7) * (nwg >> 3) + (bid >> 3);
}

// ---------------- small memory-shape kernels ----------------

__global__ __launch_bounds__(256)
void cast_kernel(const float* __restrict__ in, unsigned short* __restrict__ out, int nchunk) {
    int i = blockIdx.x * 256 + threadIdx.x;
    if (i >= nchunk) return;
    float4 a = ((const float4*)in)[i*2];
    float4 b = ((const float4*)in)[i*2+1];
    union { unsigned short u[8]; uint4 v; } r;
    r.u[0]=f2b(a.x); r.u[1]=f2b(a.y); r.u[2]=f2b(a.z); r.u[3]=f2b(a.w);
    r.u[4]=f2b(b.x); r.u[5]=f2b(b.y); r.u[6]=f2b(b.z); r.u[7]=f2b(b.w);
    ((uint4*)out)[i] = r.v;
}

// 3 weight matrices fp32 [D][D] -> bf16 [D][D]^T, blockIdx.y selects matrix
__global__ __launch_bounds__(256)
void transpose_cast3(const float* __restrict__ w0, const float* __restrict__ w1,
                     const float* __restrict__ w2, unsigned short* __restrict__ out) {
    const float* in = (blockIdx.y == 0) ? w0 : (blockIdx.y == 1) ? w1 : w2;
    unsigned short* o = out + (size_t)blockIdx.y * DIM * DIM;
    __shared__ unsigned short tile[64][66];
    int tpc = DIM >> 6;
    int tr = ((int)blockIdx.x / tpc) << 6;
    int tc = ((int)blockIdx.x % tpc) << 6;
    int t = threadIdx.x;
    #pragma unroll
    for (int i = 0; i < 16; i++) {
        int idx = t + i*256;
        int r = idx >> 6, c = idx & 63;
        tile[r][c] = f2b(in[(size_t)(tr + r)*DIM + tc + c]);
    }
    __syncthreads();
    #pragma unroll
    for (int i = 0; i < 16; i++) {
        int idx = t + i*256;
        int r = idx >> 6, c = idx & 63;
        o[(size_t)(tc + r)*DIM + tr + c] = tile[c][r];
    }
}

__global__ __launch_bounds__(256)
void transpose_b16(const unsigned short* __restrict__ in0, size_t sIn, int ldin,
                   unsigned short* __restrict__ out0, size_t sOut, int ldout, int tpc) {
    const unsigned short* in = in0 + sIn * blockIdx.y;
    unsigned short* out = out0 + sOut * blockIdx.y;
    __shared__ unsigned short tile[64][66];
    int tr = ((int)blockIdx.x / tpc) << 6;
    int tc = ((int)blockIdx.x % tpc) << 6;
    int t = threadIdx.x;
    #pragma unroll
    for (int i = 0; i < 16; i++) {
        int idx = t + i*256;
        int r = idx >> 6, c = idx & 63;
        tile[r][c] = in[(size_t)(tr + r)*ldin + tc + c];
    }
    __syncthreads();
    #pragma unroll
    for (int i = 0; i < 16; i++) {
        int idx = t + i*256;
        int r = idx >> 6, c = idx & 63;
        out[(size_t)(tc + r)*ldout + tr + c] = tile[c][r];
    }
}

__global__ __launch_bounds__(256)
void bias_concat(const float* __restrict__ bq, const float* __restrict__ bk,
                 const float* __restrict__ bv, float* __restrict__ o) {
    int i = blockIdx.x*256 + threadIdx.x;
    float v = (i < DIM) ? bq[i] : ((i < 2*DIM) ? bk[i-DIM] : bv[i-2*DIM]);
    o[i] = v;
}

// -------- 128x256 3-buffer mega-phase GEMM: 1 phase per K-tile --------
// 8 waves (2M x 4N), BK=64, triple-buffered LDS (144 KB). Phase p:
//   { 16 ds_reads of tile p (A 8, B-qn0 4, B-qn1 4) ; stage tile p+2 whole
//     (6 gloads -> buf (p+2)%3) ; lgkmcnt(8) ; vmcnt(6) ; barrier ;
//     lgkmcnt(0) ; setprio ; 32 MFMA (qn0 then qn1) ; setprio ; barrier }
// Ledger: in-flight before vmcnt = tile p+1 (6) + tile p+2 (6) = 12 ->
// vmcnt(6) publishes tile p+1 each phase, never drains to 0. WAR: stage
// target buf (p+2)%3 == (p-1)%3, last read at phase p-1, barrier-separated.
// Dummy k=0 stages in last 2 phases keep ledger uniform; vmcnt(0) post-loop.

__device__ __forceinline__ void stage1(const unsigned short* __restrict__ Xb, int ldx,
                                       unsigned short* dstBase, int h, int k0,
                                       int tid, int wid) {
    int srow = tid >> 3;
    int scol = ((tid & 7) ^ (srow & 7)) << 3;     // inverse XOR-swizzle on global src
    const unsigned short* g = Xb + (size_t)(h*128 + srow)*ldx + k0 + scol;
    unsigned short* d = dstBase + h*8192 + wid*512;
    gload_lds16(g, d);
    gload_lds16(g + (size_t)64*ldx, d + 4096);
}

#define RD_A(BUFB) do { _Pragma("unroll") for (int mf = 0; mf < 4; ++mf) { \
    fa[mf][0] = ds128(As0 + (BUFB) + aRow + mf*2048u + c0); \
    fa[mf][1] = ds128(As0 + (BUFB) + aRow + mf*2048u + c1); } } while (0)

#define RD_B(DST, BUFB, QN) do { _Pragma("unroll") for (int nf = 0; nf < 2; ++nf) { \
    DST[nf][0] = ds128(Bs0 + (BUFB) + (QN)*16384u + bRow + nf*2048u + c0); \
    DST[nf][1] = ds128(Bs0 + (BUFB) + (QN)*16384u + bRow + nf*2048u + c1); } } while (0)

template<int MODE>   // 0: bf16(acc+bias[col]) ; 1: f32(acc)
__global__ __launch_bounds__(512, 2)
void gemm3b(const unsigned short* __restrict__ A, int lda, size_t sA,
            const unsigned short* __restrict__ Bt, int ldb, size_t sB,
            const float* __restrict__ bias,
            void* __restrict__ Cout, int ldc, size_t sC,
            int N, int K)
{
    __shared__ __align__(16) unsigned short As[3][8192];    // 3 x 128x64
    __shared__ __align__(16) unsigned short Bs[3][16384];   // 3 x 256x64
    int nbn = N >> 8;
    int bid = xcd_swz((int)blockIdx.x, (int)gridDim.x);
    int bm = bid / nbn, bn = bid % nbn;
    int bz = blockIdx.y;
    int tid = threadIdx.x;
    int lane = tid & 63;
    int wid  = tid >> 6;
    int wm = (wid >> 2) & 1;          // 2 waves in M (64 rows each)
    int wn = wid & 3;                 // 4 waves in N (32 cols per quadrant)
    int rlo = lane & 15;
    int shi = lane >> 4;

    unsigned As0 = (unsigned)(uintptr_t)&As[0][0];
    unsigned Bs0 = (unsigned)(uintptr_t)&Bs[0][0];
    unsigned c0 = (unsigned)(((shi     ^ rlo) & 7) * 16);   // ks=0 swizzled 16B slot
    unsigned c1 = (unsigned)((((4+shi) ^ rlo) & 7) * 16);   // ks=1
    unsigned aRow = (unsigned)((wm*64 + rlo) * 128);        // byte offset in A tile
    unsigned bRow = (unsigned)((wn*32 + rlo) * 128);        // byte offset in B half

    f32x4 acc[2][4][2];
    #pragma unroll
    for (int a = 0; a < 2; a++)
        #pragma unroll
        for (int b = 0; b < 4; b++)
            #pragma unroll
            for (int c = 0; c < 2; c++)
                acc[a][b][c] = (f32x4){0.f,0.f,0.f,0.f};

    const unsigned short* Ab = A + sA*bz + (size_t)(bm*128)*lda;
    const unsigned short* Bb = Bt + sB*bz + (size_t)(bn*256)*ldb;

    // prologue: stage tile0 -> buf0, tile1 -> buf1 (12 loads); vmcnt(6)
    // publishes tile0, leaves tile1's 6 in flight.
    stage1(Ab, lda, &As[0][0], 0, 0,  tid, wid);
    stage1(Bb, ldb, &Bs[0][0], 0, 0,  tid, wid);
    stage1(Bb, ldb, &Bs[0][0], 1, 0,  tid, wid);
    stage1(Ab, lda, &As[1][0], 0, 64, tid, wid);
    stage1(Bb, ldb, &Bs[1][0], 0, 64, tid, wid);
    stage1(Bb, ldb, &Bs[1][0], 1, 64, tid, wid);
    __builtin_amdgcn_sched_barrier(0);
    asm volatile("s_waitcnt vmcnt(6)" ::: "memory");
    FENCE_BARRIER;

    short8 fa[4][2], fb0[2][2], fb1[2][2];
    int nt = K >> 6;          // >= 2
    int cur = 0, n1 = 1, n2 = 2;

    for (int p = 0; p < nt; ++p) {
        int kN = (p + 2 < nt) ? (p + 2) << 6 : 0;     // dummy k keeps ledger uniform
        unsigned curA = (unsigned)cur * 16384u;        // byte offsets of current buf
        unsigned curB = (unsigned)cur * 32768u;

        // reads of tile p (published at phase p-1's vmcnt)
        RD_A(curA);
        RD_B(fb0, curB, 0);
        RD_B(fb1, curB, 1);
        // stage tile p+2 -> buf n2 (== buf (p-1)%3; its readers done at barrier p-1)
        stage1(Ab, lda, &As[n2][0], 0, kN, tid, wid);
        stage1(Bb, ldb, &Bs[n2][0], 0, kN, tid, wid);
        stage1(Bb, ldb, &Bs[n2][0], 1, kN, tid, wid);
        asm volatile("s_waitcnt lgkmcnt(8)" ::: "memory");
        __builtin_amdgcn_sched_barrier(0);
        asm volatile("s_waitcnt vmcnt(6)" ::: "memory");   // publish tile p+1
        FENCE_BARRIER;
        asm volatile("s_waitcnt lgkmcnt(0)" ::: "memory");
        __builtin_amdgcn_sched_barrier(0);
        __builtin_amdgcn_s_setprio(1);
        #pragma unroll
        for (int mf = 0; mf < 4; ++mf)
            #pragma unroll
            for (int nf = 0; nf < 2; ++nf)
                #pragma unroll
                for (int ks = 0; ks < 2; ++ks)
                    acc[0][mf][nf] = __builtin_amdgcn_mfma_f32_16x16x32_bf16(
                        fa[mf][ks], fb0[nf][ks], acc[0][mf][nf], 0, 0, 0);
        #pragma unroll
        for (int mf = 0; mf < 4; ++mf)
            #pragma unroll
            for (int nf = 0; nf < 2; ++nf)
                #pragma unroll
                for (int ks = 0; ks < 2; ++ks)
                    acc[1][mf][nf] = __builtin_amdgcn_mfma_f32_16x16x32_bf16(
                        fa[mf][ks], fb1[nf][ks], acc[1][mf][nf], 0, 0, 0);
        __builtin_amdgcn_s_setprio(0);
        FENCE_BARRIER;

        int t = cur; cur = n1; n1 = n2; n2 = t;       // rotate buffers
    }

    // drain dummy-stage DMAs before LDS deallocation at wave exit
    asm volatile("s_waitcnt vmcnt(0)" ::: "memory");

    int r0 = shi << 2;
    unsigned short* Cu = (unsigned short*)Cout + sC*bz;
    float* Cf = (float*)Cout + sC*bz;
    #pragma unroll
    for (int qn = 0; qn < 2; ++qn)
        #pragma unroll
        for (int mf = 0; mf < 4; ++mf)
            #pragma unroll
            for (int nf = 0; nf < 2; ++nf) {
                int col = bn*256 + qn*128 + wn*32 + nf*16 + rlo;
                float badd = (MODE == 0) ? bias[col] : 0.f;
                #pragma unroll
                for (int r = 0; r < 4; ++r) {
                    int row = bm*128 + wm*64 + mf*16 + r0 + r;
                    float v = acc[qn][mf][nf][r];
                    if (MODE == 0) Cu[(size_t)row*ldc + col] = f2b(v + badd);
                    else           Cf[(size_t)row*ldc + col] = v;
                }
            }
}

// row softmax over 2048 fp32 scores (scaled by scl); writes bf16 probs in-place
__global__ __launch_bounds__(256)
void softmax_kernel(float* __restrict__ S, float scl) {
    int row = blockIdx.x;
    float* srow = S + (size_t)row * SEQ;
    int t = threadIdx.x;
    float4 v0 = ((const float4*)srow)[t*2];
    float4 v1 = ((const float4*)srow)[t*2+1];
    float x[8] = {v0.x*scl,v0.y*scl,v0.z*scl,v0.w*scl,v1.x*scl,v1.y*scl,v1.z*scl,v1.w*scl};
    float m = fmaxf(fmaxf(fmaxf(x[0],x[1]),fmaxf(x[2],x[3])),
                    fmaxf(fmaxf(x[4],x[5]),fmaxf(x[6],x[7])));
    #pragma unroll
    for (int off = 32; off; off >>= 1) m = fmaxf(m, __shfl_xor(m, off));
    __shared__ float redm[4], reds[4];
    int w = t >> 6;
    if ((t & 63) == 0) redm[w] = m;
    __syncthreads();
    m = fmaxf(fmaxf(redm[0], redm[1]), fmaxf(redm[2], redm[3]));
    float e[8]; float s = 0.f;
    #pragma unroll
    for (int i = 0; i < 8; i++) { e[i] = __expf(x[i] - m); s += e[i]; }
    #pragma unroll
    for (int off = 32; off; off >>= 1) s += __shfl_xor(s, off);
    if ((t & 63) == 0) reds[w] = s;
    __syncthreads();
    float inv = 1.0f / (reds[0]+reds[1]+reds[2]+reds[3]);
    union { unsigned short u[8]; uint4 v; } r;
    #pragma unroll
    for (int i = 0; i < 8; i++) r.u[i] = f2b(e[i] * inv);
    ((uint4*)srow)[t] = r.v;
}

extern "C" void kernel_launch(void* const* d_in, const int* in_sizes, int n_in,
                              void* d_out, int out_size, void* d_ws, size_t ws_size,
                              hipStream_t stream)
{
    (void)in_sizes; (void)n_in; (void)out_size;
    const float* x  = (const float*)d_in[0];
    const float* Wq = (const float*)d_in[1];
    const float* bq = (const float*)d_in[2];
    const float* Wk = (const float*)d_in[3];
    const float* bk = (const float*)d_in[4];
    const float* Wv = (const float*)d_in[5];
    const float* bv = (const float*)d_in[6];
    float* out = (float*)d_out;

    unsigned short* qkv = (unsigned short*)d_ws;                    // [8192][3072]
    unsigned short* vt  = qkv + (size_t)MTOT*QKVN;                  // [4][1024][2048]
    float* biasc = (float*)(vt + (size_t)NB*DIM*SEQ);               // [3072]
    char* ovl = (char*)biasc + 65536;
    unsigned short* xb    = (unsigned short*)ovl;                   // [8192][1024]
    unsigned short* wqkvt = xb + (size_t)MTOT*DIM;                  // [3072][1024]
    float* scores = (float*)ovl;                                    // [bpp][2048][2048]

    size_t base = (size_t)MTOT*QKVN*2 + (size_t)NB*DIM*SEQ*2 + 65536;
    int bpp = 1;
    if (base + 4*(size_t)SEQ*SEQ*4 <= ws_size) bpp = 4;
    else if (base + 2*(size_t)SEQ*SEQ*4 <= ws_size) bpp = 2;

    cast_kernel<<<MTOT*DIM/8/256, 256, 0, stream>>>(x, xb, MTOT*DIM/8);
    transpose_cast3<<<dim3(256, 3), 256, 0, stream>>>(Wq, Wk, Wv, wqkvt);
    bias_concat<<<QKVN/256, 256, 0, stream>>>(bq, bk, bv, biasc);

    // fused QKV projection: [8192,1024] @ [3072,1024]^T, grid 64x12=768 (3.0 rounds)
    gemm3b<0><<<dim3((MTOT/128)*(QKVN/256)), 512, 0, stream>>>(
        xb, DIM, 0, wqkvt, DIM, 0, biasc, qkv, QKVN, 0, QKVN, DIM);

    transpose_b16<<<dim3((SEQ/64)*(DIM/64), NB), 256, 0, stream>>>(
        qkv + 2*DIM, (size_t)SEQ*QKVN, QKVN, vt, (size_t)DIM*SEQ, SEQ, DIM/64);

    const float scl = 1.0f / 32.0f;   // 1/sqrt(1024), folded into softmax
    for (int p = 0; p < NB; p += bpp) {
        const unsigned short* qp = qkv + (size_t)p*SEQ*QKVN;
        // scores: grid 16x8=128 per batch (x), bpp batches (y) -> 512 blocks
        gemm3b<1><<<dim3((SEQ/128)*(SEQ/256), bpp), 512, 0, stream>>>(
            qp,       QKVN, (size_t)SEQ*QKVN,
            qp + DIM, QKVN, (size_t)SEQ*QKVN,
            nullptr, scores, SEQ, (size_t)SEQ*SEQ, SEQ, DIM);
        softmax_kernel<<<bpp*SEQ, 256, 0, stream>>>(scores, scl);
        // PV: grid 16x4=64 per batch -> 256 blocks (1.0 round)
        gemm3b<1><<<dim3((SEQ/128)*(DIM/256), bpp), 512, 0, stream>>>(
            (const unsigned short*)scores, 2*SEQ, (size_t)SEQ*2*SEQ,
            vt + (size_t)p*DIM*SEQ,        SEQ,   (size_t)DIM*SEQ,
            nullptr, out + (size_t)p*SEQ*DIM, DIM, (size_t)SEQ*DIM, DIM, SEQ);
    }
}

// Round 13
// 180.502 us; speedup vs baseline: 1.0739x; 1.0739x over previous
//
#include <hip/hip_runtime.h>
#include <stdint.h>

#define SEQ 2048
#define DIM 1024
#define NB 4
#define MTOT (NB*SEQ)
#define QKVN (3*DIM)

typedef __attribute__((ext_vector_type(8))) short short8;
typedef __attribute__((ext_vector_type(4))) float f32x4;

__device__ __forceinline__ unsigned short f2b(float f) {
    union { float f; unsigned int u; } v; v.f = f;
    return (unsigned short)((v.u + 0x7FFFu + ((v.u >> 16) & 1u)) >> 16);
}
__device__ __forceinline__ float b2f(unsigned short u) {
    union { unsigned int i; float f; } v; v.i = ((unsigned int)u) << 16; return v.f;
}

__device__ __forceinline__ void gload_lds16(const unsigned short* g, unsigned short* l) {
    __builtin_amdgcn_global_load_lds(
        (const __attribute__((address_space(1))) void*)g,
        (__attribute__((address_space(3))) void*)l, 16, 0, 0);
}

// inline-asm LDS read: invisible to backend waitcnt insertion; dependency on the
// LDS-DMA is managed ONLY by our counted vmcnt/lgkmcnt ledger.
__device__ __forceinline__ short8 ds128(unsigned addr) {
    short8 r;
    asm volatile("ds_read_b128 %0, %1" : "=v"(r) : "v"(addr));
    return r;
}

#define FENCE_BARRIER do { asm volatile("" ::: "memory"); \
    __builtin_amdgcn_s_barrier(); asm volatile("" ::: "memory"); } while (0)

__device__ __forceinline__ int xcd_swz(int bid, int nwg) {
    if (nwg & 7) return bid;
    return (bid & 7) * (nwg >> 3) + (bid >> 3);
}

// ---------------- small memory-shape kernels ----------------

__global__ __launch_bounds__(256)
void cast_kernel(const float* __restrict__ in, unsigned short* __restrict__ out, int nchunk) {
    int i = blockIdx.x * 256 + threadIdx.x;
    if (i >= nchunk) return;
    float4 a = ((const float4*)in)[i*2];
    float4 b = ((const float4*)in)[i*2+1];
    union { unsigned short u[8]; uint4 v; } r;
    r.u[0]=f2b(a.x); r.u[1]=f2b(a.y); r.u[2]=f2b(a.z); r.u[3]=f2b(a.w);
    r.u[4]=f2b(b.x); r.u[5]=f2b(b.y); r.u[6]=f2b(b.z); r.u[7]=f2b(b.w);
    ((uint4*)out)[i] = r.v;
}

// 3 weight matrices fp32 [D][D] -> bf16 [D][D]^T, blockIdx.y selects matrix
__global__ __launch_bounds__(256)
void transpose_cast3(const float* __restrict__ w0, const float* __restrict__ w1,
                     const float* __restrict__ w2, unsigned short* __restrict__ out) {
    const float* in = (blockIdx.y == 0) ? w0 : (blockIdx.y == 1) ? w1 : w2;
    unsigned short* o = out + (size_t)blockIdx.y * DIM * DIM;
    __shared__ unsigned short tile[64][66];
    int tpc = DIM >> 6;
    int tr = ((int)blockIdx.x / tpc) << 6;
    int tc = ((int)blockIdx.x % tpc) << 6;
    int t = threadIdx.x;
    #pragma unroll
    for (int i = 0; i < 16; i++) {
        int idx = t + i*256;
        int r = idx >> 6, c = idx & 63;
        tile[r][c] = f2b(in[(size_t)(tr + r)*DIM + tc + c]);
    }
    __syncthreads();
    #pragma unroll
    for (int i = 0; i < 16; i++) {
        int idx = t + i*256;
        int r = idx >> 6, c = idx & 63;
        o[(size_t)(tc + r)*DIM + tr + c] = tile[c][r];
    }
}

__global__ __launch_bounds__(256)
void transpose_b16(const unsigned short* __restrict__ in0, size_t sIn, int ldin,
                   unsigned short* __restrict__ out0, size_t sOut, int ldout, int tpc) {
    const unsigned short* in = in0 + sIn * blockIdx.y;
    unsigned short* out = out0 + sOut * blockIdx.y;
    __shared__ unsigned short tile[64][66];
    int tr = ((int)blockIdx.x / tpc) << 6;
    int tc = ((int)blockIdx.x % tpc) << 6;
    int t = threadIdx.x;
    #pragma unroll
    for (int i = 0; i < 16; i++) {
        int idx = t + i*256;
        int r = idx >> 6, c = idx & 63;
        tile[r][c] = in[(size_t)(tr + r)*ldin + tc + c];
    }
    __syncthreads();
    #pragma unroll
    for (int i = 0; i < 16; i++) {
        int idx = t + i*256;
        int r = idx >> 6, c = idx & 63;
        out[(size_t)(tc + r)*ldout + tr + c] = tile[c][r];
    }
}

__global__ __launch_bounds__(256)
void bias_concat(const float* __restrict__ bq, const float* __restrict__ bk,
                 const float* __restrict__ bv, float* __restrict__ o) {
    int i = blockIdx.x*256 + threadIdx.x;
    float v = (i < DIM) ? bq[i] : ((i < 2*DIM) ? bk[i-DIM] : bv[i-2*DIM]);
    o[i] = v;
}

// -------- 128x256 4-phase pipelined GEMM (round-8 checkpoint structure) --------
// 8 waves (2M x 4N), BK=64, 2 K-tiles/iter (E=buf0, O=buf1). Per-wave 64x64,
// acc = 16 f32x4 (64 AGPR). LDS 96KB, XOR-swizzled via pre-swizzled global src.
// Stage slots: p1 O.Bh1 | p2 E2.A + E2.Bh0, vmcnt(4) (publish O) |
//              p3 E2.Bh1 | p4 O2.A + O2.Bh0, vmcnt(4) (publish E2).
// MODE 0: bf16(acc + bias[col]); MODE 1: f32(acc); MODE 2: bf16(acc * scale)

__device__ __forceinline__ void stage1(const unsigned short* __restrict__ Xb, int ldx,
                                       unsigned short* dstBase, int h, int k0,
                                       int tid, int wid) {
    int srow = tid >> 3;
    int scol = ((tid & 7) ^ (srow & 7)) << 3;     // inverse XOR-swizzle on global src
    const unsigned short* g = Xb + (size_t)(h*128 + srow)*ldx + k0 + scol;
    unsigned short* d = dstBase + h*8192 + wid*512;
    gload_lds16(g, d);
    gload_lds16(g + (size_t)64*ldx, d + 4096);
}

#define RD_A(BUF) do { _Pragma("unroll") for (int mf = 0; mf < 4; ++mf) { \
    fa[mf][0] = ds128(As0 + (BUF)*16384u + aRow + mf*2048u + c0); \
    fa[mf][1] = ds128(As0 + (BUF)*16384u + aRow + mf*2048u + c1); } } while (0)

#define RD_B(BUF, QN) do { _Pragma("unroll") for (int nf = 0; nf < 2; ++nf) { \
    fb[nf][0] = ds128(Bs0 + (BUF)*32768u + (QN)*16384u + bRow + nf*2048u + c0); \
    fb[nf][1] = ds128(Bs0 + (BUF)*32768u + (QN)*16384u + bRow + nf*2048u + c1); } } while (0)

#define MMA_PH(QN) do { \
    asm volatile("s_waitcnt lgkmcnt(0)" ::: "memory"); \
    __builtin_amdgcn_sched_barrier(0); \
    __builtin_amdgcn_s_setprio(1); \
    _Pragma("unroll") for (int mf = 0; mf < 4; ++mf) \
      _Pragma("unroll") for (int nf = 0; nf < 2; ++nf) \
        _Pragma("unroll") for (int ks = 0; ks < 2; ++ks) \
          acc[QN][mf][nf] = __builtin_amdgcn_mfma_f32_16x16x32_bf16( \
              fa[mf][ks], fb[nf][ks], acc[QN][mf][nf], 0, 0, 0); \
    __builtin_amdgcn_s_setprio(0); \
} while (0)

template<int MODE>
__global__ __launch_bounds__(512, 2)
void gemm4p(const unsigned short* __restrict__ A, int lda, size_t sA,
            const unsigned short* __restrict__ Bt, int ldb, size_t sB,
            const float* __restrict__ bias,
            void* __restrict__ Cout, int ldc, size_t sC,
            int N, int K, float scale)
{
    __shared__ __align__(16) unsigned short As[2][8192];
    __shared__ __align__(16) unsigned short Bs[2][16384];
    int nbn = N >> 8;
    int bid = xcd_swz((int)blockIdx.x, (int)gridDim.x);
    int bm = bid / nbn, bn = bid % nbn;
    int bz = blockIdx.y;
    int tid = threadIdx.x;
    int lane = tid & 63;
    int wid  = tid >> 6;
    int wm = (wid >> 2) & 1;          // 2 waves in M (64 rows each)
    int wn = wid & 3;                 // 4 waves in N (32 cols each per quadrant)
    int rlo = lane & 15;
    int shi = lane >> 4;

    unsigned As0 = (unsigned)(uintptr_t)&As[0][0];
    unsigned Bs0 = (unsigned)(uintptr_t)&Bs[0][0];
    unsigned c0 = (unsigned)(((shi     ^ rlo) & 7) * 16);   // ks=0 swizzled 16B slot
    unsigned c1 = (unsigned)((((4+shi) ^ rlo) & 7) * 16);   // ks=1
    unsigned aRow = (unsigned)((wm*64 + rlo) * 128);        // byte offset in A tile
    unsigned bRow = (unsigned)((wn*32 + rlo) * 128);        // byte offset in B half

    f32x4 acc[2][4][2];
    #pragma unroll
    for (int a = 0; a < 2; a++)
        #pragma unroll
        for (int b = 0; b < 4; b++)
            #pragma unroll
            for (int c = 0; c < 2; c++)
                acc[a][b][c] = (f32x4){0.f,0.f,0.f,0.f};

    const unsigned short* Ab = A + sA*bz + (size_t)(bm*128)*lda;
    const unsigned short* Bb = Bt + sB*bz + (size_t)(bn*256)*ldb;

    // prologue: tile E {A, Bh0, Bh1} (6 loads) + tile O {A, Bh0} (4 loads);
    // vmcnt(4) drains E, leaves O's 4 in flight.
    stage1(Ab, lda, &As[0][0], 0, 0,  tid, wid);
    stage1(Bb, ldb, &Bs[0][0], 0, 0,  tid, wid);
    stage1(Bb, ldb, &Bs[0][0], 1, 0,  tid, wid);
    stage1(Ab, lda, &As[1][0], 0, 64, tid, wid);
    stage1(Bb, ldb, &Bs[1][0], 0, 64, tid, wid);
    __builtin_amdgcn_sched_barrier(0);
    asm volatile("s_waitcnt vmcnt(4)" ::: "memory");
    FENCE_BARRIER;

    short8 fa[4][2], fb[2][2];
    int nt = K >> 6;          // even, >= 4
    int nit = nt >> 1;

    for (int it = 0; it < nit; ++it) {
        int kO  = (2*it + 1) << 6;
        int kE2 = (2*it + 2 < nt) ? (2*it + 2) << 6 : 0;   // dummy k keeps ledger uniform
        int kO2 = (2*it + 3 < nt) ? (2*it + 3) << 6 : 0;

        // p1: reads A_E (8) + B_E qn0 (4); stage O.Bh1; pace; MFMA E qn0
        RD_A(0); RD_B(0, 0);
        stage1(Bb, ldb, &Bs[1][0], 1, kO, tid, wid);
        asm volatile("s_waitcnt lgkmcnt(8)" ::: "memory");
        FENCE_BARRIER; MMA_PH(0); FENCE_BARRIER;
        // p2: reads B_E qn1 (4); stage E2.A + E2.Bh0; publish O; MFMA E qn1
        RD_B(0, 1);
        stage1(Ab, lda, &As[0][0], 0, kE2, tid, wid);
        stage1(Bb, ldb, &Bs[0][0], 0, kE2, tid, wid);
        __builtin_amdgcn_sched_barrier(0);
        asm volatile("s_waitcnt vmcnt(4)" ::: "memory");
        FENCE_BARRIER; MMA_PH(1); FENCE_BARRIER;
        // p3: reads A_O (8) + B_O qn0 (4); stage E2.Bh1; pace; MFMA O qn0
        RD_A(1); RD_B(1, 0);
        stage1(Bb, ldb, &Bs[0][0], 1, kE2, tid, wid);
        asm volatile("s_waitcnt lgkmcnt(8)" ::: "memory");
        FENCE_BARRIER; MMA_PH(0); FENCE_BARRIER;
        // p4: reads B_O qn1 (4); stage O2.A + O2.Bh0; publish E2; MFMA O qn1
        RD_B(1, 1);
        stage1(Ab, lda, &As[1][0], 0, kO2, tid, wid);
        stage1(Bb, ldb, &Bs[1][0], 0, kO2, tid, wid);
        __builtin_amdgcn_sched_barrier(0);
        asm volatile("s_waitcnt vmcnt(4)" ::: "memory");
        FENCE_BARRIER; MMA_PH(1); FENCE_BARRIER;
    }

    // drain dummy-stage DMAs before LDS deallocation at wave exit
    asm volatile("s_waitcnt vmcnt(0)" ::: "memory");

    int r0 = shi << 2;
    unsigned short* Cu = (unsigned short*)Cout + sC*bz;
    float* Cf = (float*)Cout + sC*bz;
    #pragma unroll
    for (int qn = 0; qn < 2; ++qn)
        #pragma unroll
        for (int mf = 0; mf < 4; ++mf)
            #pragma unroll
            for (int nf = 0; nf < 2; ++nf) {
                int col = bn*256 + qn*128 + wn*32 + nf*16 + rlo;
                float badd = (MODE == 0) ? bias[col] : 0.f;
                #pragma unroll
                for (int r = 0; r < 4; ++r) {
                    int row = bm*128 + wm*64 + mf*16 + r0 + r;
                    float v = acc[qn][mf][nf][r];
                    if (MODE == 0)      Cu[(size_t)row*ldc + col] = f2b(v + badd);
                    else if (MODE == 1) Cf[(size_t)row*ldc + col] = v;
                    else                Cu[(size_t)row*ldc + col] = f2b(v * scale);
                }
            }
}

// row softmax over 2048 bf16 z-scores, in place (z already scaled by 1/32)
__global__ __launch_bounds__(256)
void softmax_bf16(unsigned short* __restrict__ S) {
    int row = blockIdx.x;
    unsigned short* srow = S + (size_t)row * SEQ;
    int t = threadIdx.x;
    uint4 raw = ((const uint4*)srow)[t];
    const unsigned short* u = (const unsigned short*)&raw;
    float x[8];
    #pragma unroll
    for (int i = 0; i < 8; i++) x[i] = b2f(u[i]);
    float m = fmaxf(fmaxf(fmaxf(x[0],x[1]),fmaxf(x[2],x[3])),
                    fmaxf(fmaxf(x[4],x[5]),fmaxf(x[6],x[7])));
    #pragma unroll
    for (int off = 32; off; off >>= 1) m = fmaxf(m, __shfl_xor(m, off));
    __shared__ float redm[4], reds[4];
    int w = t >> 6;
    if ((t & 63) == 0) redm[w] = m;
    __syncthreads();
    m = fmaxf(fmaxf(redm[0], redm[1]), fmaxf(redm[2], redm[3]));
    float e[8]; float s = 0.f;
    #pragma unroll
    for (int i = 0; i < 8; i++) { e[i] = __expf(x[i] - m); s += e[i]; }
    #pragma unroll
    for (int off = 32; off; off >>= 1) s += __shfl_xor(s, off);
    if ((t & 63) == 0) reds[w] = s;
    __syncthreads();
    float inv = 1.0f / (reds[0]+reds[1]+reds[2]+reds[3]);
    union { unsigned short u[8]; uint4 v; } r;
    #pragma unroll
    for (int i = 0; i < 8; i++) r.u[i] = f2b(e[i] * inv);
    ((uint4*)srow)[t] = r.v;   // all cross-wave reads pre-barrier -> in-place safe
}

extern "C" void kernel_launch(void* const* d_in, const int* in_sizes, int n_in,
                              void* d_out, int out_size, void* d_ws, size_t ws_size,
                              hipStream_t stream)
{
    (void)in_sizes; (void)n_in; (void)out_size;
    const float* x  = (const float*)d_in[0];
    const float* Wq = (const float*)d_in[1];
    const float* bq = (const float*)d_in[2];
    const float* Wk = (const float*)d_in[3];
    const float* bk = (const float*)d_in[4];
    const float* Wv = (const float*)d_in[5];
    const float* bv = (const float*)d_in[6];
    float* out = (float*)d_out;

    unsigned short* qkv = (unsigned short*)d_ws;                    // [8192][3072]
    unsigned short* vt  = qkv + (size_t)MTOT*QKVN;                  // [4][1024][2048]
    float* biasc = (float*)(vt + (size_t)NB*DIM*SEQ);               // [3072]
    char* ovl = (char*)biasc + 65536;
    unsigned short* xb    = (unsigned short*)ovl;                   // [8192][1024]
    unsigned short* wqkvt = xb + (size_t)MTOT*DIM;                  // [3072][1024]
    unsigned short* scoresB = (unsigned short*)ovl;                 // [bpp][2048][2048] bf16

    size_t base = (size_t)MTOT*QKVN*2 + (size_t)NB*DIM*SEQ*2 + 65536;
    int bpp = 1;
    if (base + 4*(size_t)SEQ*SEQ*2 <= ws_size) bpp = 4;
    else if (base + 2*(size_t)SEQ*SEQ*2 <= ws_size) bpp = 2;

    cast_kernel<<<MTOT*DIM/8/256, 256, 0, stream>>>(x, xb, MTOT*DIM/8);
    transpose_cast3<<<dim3(256, 3), 256, 0, stream>>>(Wq, Wk, Wv, wqkvt);
    bias_concat<<<QKVN/256, 256, 0, stream>>>(bq, bk, bv, biasc);

    // fused QKV projection: [8192,1024] @ [3072,1024]^T, grid 64x12=768 (3.0 rounds)
    gemm4p<0><<<dim3((MTOT/128)*(QKVN/256)), 512, 0, stream>>>(
        xb, DIM, 0, wqkvt, DIM, 0, biasc, qkv, QKVN, 0, QKVN, DIM, 1.f);

    transpose_b16<<<dim3((SEQ/64)*(DIM/64), NB), 256, 0, stream>>>(
        qkv + 2*DIM, (size_t)SEQ*QKVN, QKVN, vt, (size_t)DIM*SEQ, SEQ, DIM/64);

    const float scl = 1.0f / 32.0f;   // 1/sqrt(1024), folded into scores GEMM write
    for (int p = 0; p < NB; p += bpp) {
        const unsigned short* qp = qkv + (size_t)p*SEQ*QKVN;
        // scores: z = (Q.K^T)/32 written as bf16 (halves softmax-path HBM traffic)
        gemm4p<2><<<dim3((SEQ/128)*(SEQ/256), bpp), 512, 0, stream>>>(
            qp,       QKVN, (size_t)SEQ*QKVN,
            qp + DIM, QKVN, (size_t)SEQ*QKVN,
            nullptr, scoresB, SEQ, (size_t)SEQ*SEQ, SEQ, DIM, scl);
        softmax_bf16<<<bpp*SEQ, 256, 0, stream>>>(scoresB);
        // PV: out = P . V, grid 16x4=64 per batch -> 256 blocks (1.0 round)
        gemm4p<1><<<dim3((SEQ/128)*(DIM/256), bpp), 512, 0, stream>>>(
            scoresB, SEQ, (size_t)SEQ*SEQ,
            vt + (size_t)p*DIM*SEQ, SEQ, (size_t)DIM*SEQ,
            nullptr, out + (size_t)p*SEQ*DIM, DIM, (size_t)SEQ*DIM, DIM, SEQ, 1.f);
    }
}

// Round 14
// 178.994 us; speedup vs baseline: 1.0829x; 1.0084x over previous
//
#include <hip/hip_runtime.h>
#include <stdint.h>

#define SEQ 2048
#define DIM 1024
#define NB 4
#define MTOT (NB*SEQ)
#define QKVN (3*DIM)

typedef __attribute__((ext_vector_type(8))) short short8;
typedef __attribute__((ext_vector_type(4))) float f32x4;

__device__ __forceinline__ unsigned short f2b(float f) {
    union { float f; unsigned int u; } v; v.f = f;
    return (unsigned short)((v.u + 0x7FFFu + ((v.u >> 16) & 1u)) >> 16);
}
__device__ __forceinline__ float b2f(unsigned short u) {
    union { unsigned int i; float f; } v; v.i = ((unsigned int)u) << 16; return v.f;
}

__device__ __forceinline__ void gload_lds16(const unsigned short* g, unsigned short* l) {
    __builtin_amdgcn_global_load_lds(
        (const __attribute__((address_space(1))) void*)g,
        (__attribute__((address_space(3))) void*)l, 16, 0, 0);
}

// inline-asm LDS read: invisible to backend waitcnt insertion; dependency on the
// LDS-DMA is managed ONLY by our counted vmcnt/lgkmcnt ledger.
__device__ __forceinline__ short8 ds128(unsigned addr) {
    short8 r;
    asm volatile("ds_read_b128 %0, %1" : "=v"(r) : "v"(addr));
    return r;
}

#define FENCE_BARRIER do { asm volatile("" ::: "memory"); \
    __builtin_amdgcn_s_barrier(); asm volatile("" ::: "memory"); } while (0)

__device__ __forceinline__ int xcd_swz(int bid, int nwg) {
    if (nwg & 7) return bid;
    return (bid & 7) * (nwg >> 3) + (bid >> 3);
}

// ---------------- small memory-shape kernels ----------------

__global__ __launch_bounds__(256)
void cast_kernel(const float* __restrict__ in, unsigned short* __restrict__ out, int nchunk) {
    int i = blockIdx.x * 256 + threadIdx.x;
    if (i >= nchunk) return;
    float4 a = ((const float4*)in)[i*2];
    float4 b = ((const float4*)in)[i*2+1];
    union { unsigned short u[8]; uint4 v; } r;
    r.u[0]=f2b(a.x); r.u[1]=f2b(a.y); r.u[2]=f2b(a.z); r.u[3]=f2b(a.w);
    r.u[4]=f2b(b.x); r.u[5]=f2b(b.y); r.u[6]=f2b(b.z); r.u[7]=f2b(b.w);
    ((uint4*)out)[i] = r.v;
}

// 3 weight matrices fp32 [D][D] -> bf16 [D][D]^T, blockIdx.y selects matrix
__global__ __launch_bounds__(256)
void transpose_cast3(const float* __restrict__ w0, const float* __restrict__ w1,
                     const float* __restrict__ w2, unsigned short* __restrict__ out) {
    const float* in = (blockIdx.y == 0) ? w0 : (blockIdx.y == 1) ? w1 : w2;
    unsigned short* o = out + (size_t)blockIdx.y * DIM * DIM;
    __shared__ unsigned short tile[64][66];
    int tpc = DIM >> 6;
    int tr = ((int)blockIdx.x / tpc) << 6;
    int tc = ((int)blockIdx.x % tpc) << 6;
    int t = threadIdx.x;
    #pragma unroll
    for (int i = 0; i < 16; i++) {
        int idx = t + i*256;
        int r = idx >> 6, c = idx & 63;
        tile[r][c] = f2b(in[(size_t)(tr + r)*DIM + tc + c]);
    }
    __syncthreads();
    #pragma unroll
    for (int i = 0; i < 16; i++) {
        int idx = t + i*256;
        int r = idx >> 6, c = idx & 63;
        o[(size_t)(tc + r)*DIM + tr + c] = tile[c][r];
    }
}

__global__ __launch_bounds__(256)
void transpose_b16(const unsigned short* __restrict__ in0, size_t sIn, int ldin,
                   unsigned short* __restrict__ out0, size_t sOut, int ldout, int tpc) {
    const unsigned short* in = in0 + sIn * blockIdx.y;
    unsigned short* out = out0 + sOut * blockIdx.y;
    __shared__ unsigned short tile[64][66];
    int tr = ((int)blockIdx.x / tpc) << 6;
    int tc = ((int)blockIdx.x % tpc) << 6;
    int t = threadIdx.x;
    #pragma unroll
    for (int i = 0; i < 16; i++) {
        int idx = t + i*256;
        int r = idx >> 6, c = idx & 63;
        tile[r][c] = in[(size_t)(tr + r)*ldin + tc + c];
    }
    __syncthreads();
    #pragma unroll
    for (int i = 0; i < 16; i++) {
        int idx = t + i*256;
        int r = idx >> 6, c = idx & 63;
        out[(size_t)(tc + r)*ldout + tr + c] = tile[c][r];
    }
}

__global__ __launch_bounds__(256)
void bias_concat(const float* __restrict__ bq, const float* __restrict__ bk,
                 const float* __restrict__ bv, float* __restrict__ o) {
    int i = blockIdx.x*256 + threadIdx.x;
    float v = (i < DIM) ? bq[i] : ((i < 2*DIM) ? bk[i-DIM] : bv[i-2*DIM]);
    o[i] = v;
}

// -------- 64x256 4-phase pipelined GEMM, 2 blocks/CU --------
// Same verified r8 ledger, BM=64: LDS 80KB (As[2] 16KB + Bs[2] 64KB) -> 2
// blocks/CU co-resident; stalled phases of one block hidden by the other's
// MFMA (m114 overlap). 8 waves (2M x 4N): per-wave 32x64, acc 32 AGPR.
// loads/tile: A=1 gload, Bh0=2, Bh1=2 (5). Prologue 8 loads -> vmcnt(3).
// Slots: p1 O.Bh1 | p2 E2.A + E2.Bh0, vmcnt(3) (publish O) |
//        p3 E2.Bh1 | p4 O2.A + O2.Bh0, vmcnt(3) (publish E2).
// WAR identical to r8: A read p1/p3 only (held), Bh0 read qn0-phase only,
// Bh1 qn1-phase only; every stage >=1 barrier after its target's last read.
// MODE 0: bf16(acc+bias[col]); MODE 1: f32(acc); MODE 2: bf16(acc*scale)

__device__ __forceinline__ void stageA64(const unsigned short* __restrict__ Xb, int ldx,
                                         unsigned short* dstBase, int k0,
                                         int tid, int wid) {
    int srow = tid >> 3;
    int scol = ((tid & 7) ^ (srow & 7)) << 3;     // inverse XOR-swizzle on global src
    gload_lds16(Xb + (size_t)srow*ldx + k0 + scol, dstBase + wid*512);
}

__device__ __forceinline__ void stageB(const unsigned short* __restrict__ Xb, int ldx,
                                       unsigned short* dstBase, int h, int k0,
                                       int tid, int wid) {
    int srow = tid >> 3;
    int scol = ((tid & 7) ^ (srow & 7)) << 3;
    const unsigned short* g = Xb + (size_t)(h*128 + srow)*ldx + k0 + scol;
    unsigned short* d = dstBase + h*8192 + wid*512;
    gload_lds16(g, d);
    gload_lds16(g + (size_t)64*ldx, d + 4096);
}

#define RD_A(BUF) do { _Pragma("unroll") for (int mf = 0; mf < 2; ++mf) { \
    fa[mf][0] = ds128(As0 + (BUF)*8192u + aRow + mf*2048u + c0); \
    fa[mf][1] = ds128(As0 + (BUF)*8192u + aRow + mf*2048u + c1); } } while (0)

#define RD_B(BUF, QN) do { _Pragma("unroll") for (int nf = 0; nf < 2; ++nf) { \
    fb[nf][0] = ds128(Bs0 + (BUF)*32768u + (QN)*16384u + bRow + nf*2048u + c0); \
    fb[nf][1] = ds128(Bs0 + (BUF)*32768u + (QN)*16384u + bRow + nf*2048u + c1); } } while (0)

#define MMA_PH(QN) do { \
    asm volatile("s_waitcnt lgkmcnt(0)" ::: "memory"); \
    __builtin_amdgcn_sched_barrier(0); \
    __builtin_amdgcn_s_setprio(1); \
    _Pragma("unroll") for (int mf = 0; mf < 2; ++mf) \
      _Pragma("unroll") for (int nf = 0; nf < 2; ++nf) \
        _Pragma("unroll") for (int ks = 0; ks < 2; ++ks) \
          acc[QN][mf][nf] = __builtin_amdgcn_mfma_f32_16x16x32_bf16( \
              fa[mf][ks], fb[nf][ks], acc[QN][mf][nf], 0, 0, 0); \
    __builtin_amdgcn_s_setprio(0); \
} while (0)

template<int MODE>
__global__ __launch_bounds__(512, 2)
void gemm4p(const unsigned short* __restrict__ A, int lda, size_t sA,
            const unsigned short* __restrict__ Bt, int ldb, size_t sB,
            const float* __restrict__ bias,
            void* __restrict__ Cout, int ldc, size_t sC,
            int N, int K, float scale)
{
    __shared__ __align__(16) unsigned short As[2][4096];     // 2 x 64x64 (16KB)
    __shared__ __align__(16) unsigned short Bs[2][16384];    // 2 x 256x64 (64KB)
    int nbn = N >> 8;
    int bid = xcd_swz((int)blockIdx.x, (int)gridDim.x);
    int bm = bid / nbn, bn = bid % nbn;
    int bz = blockIdx.y;
    int tid = threadIdx.x;
    int lane = tid & 63;
    int wid  = tid >> 6;
    int wm = (wid >> 2) & 1;          // 2 waves in M (32 rows each)
    int wn = wid & 3;                 // 4 waves in N (32 cols per quadrant)
    int rlo = lane & 15;
    int shi = lane >> 4;

    unsigned As0 = (unsigned)(uintptr_t)&As[0][0];
    unsigned Bs0 = (unsigned)(uintptr_t)&Bs[0][0];
    unsigned c0 = (unsigned)(((shi     ^ rlo) & 7) * 16);   // ks=0 swizzled 16B slot
    unsigned c1 = (unsigned)((((4+shi) ^ rlo) & 7) * 16);   // ks=1
    unsigned aRow = (unsigned)((wm*32 + rlo) * 128);        // byte offset in A tile
    unsigned bRow = (unsigned)((wn*32 + rlo) * 128);        // byte offset in B half

    f32x4 acc[2][2][2];
    #pragma unroll
    for (int a = 0; a < 2; a++)
        #pragma unroll
        for (int b = 0; b < 2; b++)
            #pragma unroll
            for (int c = 0; c < 2; c++)
                acc[a][b][c] = (f32x4){0.f,0.f,0.f,0.f};

    const unsigned short* Ab = A + sA*bz + (size_t)(bm*64)*lda;
    const unsigned short* Bb = Bt + sB*bz + (size_t)(bn*256)*ldb;

    // prologue: tile E {A, Bh0, Bh1} (5 loads) + tile O {A, Bh0} (3 loads);
    // vmcnt(3) drains E, leaves O's 3 in flight.
    stageA64(Ab, lda, &As[0][0], 0,  tid, wid);
    stageB(Bb, ldb, &Bs[0][0], 0, 0,  tid, wid);
    stageB(Bb, ldb, &Bs[0][0], 1, 0,  tid, wid);
    stageA64(Ab, lda, &As[1][0], 64, tid, wid);
    stageB(Bb, ldb, &Bs[1][0], 0, 64, tid, wid);
    __builtin_amdgcn_sched_barrier(0);
    asm volatile("s_waitcnt vmcnt(3)" ::: "memory");
    FENCE_BARRIER;

    short8 fa[2][2], fb[2][2];
    int nt = K >> 6;          // even, >= 4
    int nit = nt >> 1;

    for (int it = 0; it < nit; ++it) {
        int kO  = (2*it + 1) << 6;
        int kE2 = (2*it + 2 < nt) ? (2*it + 2) << 6 : 0;   // dummy k keeps ledger uniform
        int kO2 = (2*it + 3 < nt) ? (2*it + 3) << 6 : 0;

        // p1: reads A_E (4) + B_E qn0 (4); stage O.Bh1; pace; MFMA E qn0
        RD_A(0); RD_B(0, 0);
        stageB(Bb, ldb, &Bs[1][0], 1, kO, tid, wid);
        asm volatile("s_waitcnt lgkmcnt(4)" ::: "memory");
        FENCE_BARRIER; MMA_PH(0); FENCE_BARRIER;
        // p2: reads B_E qn1 (4); stage E2.A + E2.Bh0; publish O; MFMA E qn1
        RD_B(0, 1);
        stageA64(Ab, lda, &As[0][0], kE2, tid, wid);
        stageB(Bb, ldb, &Bs[0][0], 0, kE2, tid, wid);
        __builtin_amdgcn_sched_barrier(0);
        asm volatile("s_waitcnt vmcnt(3)" ::: "memory");
        FENCE_BARRIER; MMA_PH(1); FENCE_BARRIER;
        // p3: reads A_O (4) + B_O qn0 (4); stage E2.Bh1; pace; MFMA O qn0
        RD_A(1); RD_B(1, 0);
        stageB(Bb, ldb, &Bs[0][0], 1, kE2, tid, wid);
        asm volatile("s_waitcnt lgkmcnt(4)" ::: "memory");
        FENCE_BARRIER; MMA_PH(0); FENCE_BARRIER;
        // p4: reads B_O qn1 (4); stage O2.A + O2.Bh0; publish E2; MFMA O qn1
        RD_B(1, 1);
        stageA64(Ab, lda, &As[1][0], kO2, tid, wid);
        stageB(Bb, ldb, &Bs[1][0], 0, kO2, tid, wid);
        __builtin_amdgcn_sched_barrier(0);
        asm volatile("s_waitcnt vmcnt(3)" ::: "memory");
        FENCE_BARRIER; MMA_PH(1); FENCE_BARRIER;
    }

    // drain dummy-stage DMAs before LDS deallocation at wave exit
    asm volatile("s_waitcnt vmcnt(0)" ::: "memory");

    int r0 = shi << 2;
    unsigned short* Cu = (unsigned short*)Cout + sC*bz;
    float* Cf = (float*)Cout + sC*bz;
    #pragma unroll
    for (int qn = 0; qn < 2; ++qn)
        #pragma unroll
        for (int mf = 0; mf < 2; ++mf)
            #pragma unroll
            for (int nf = 0; nf < 2; ++nf) {
                int col = bn*256 + qn*128 + wn*32 + nf*16 + rlo;
                float badd = (MODE == 0) ? bias[col] : 0.f;
                #pragma unroll
                for (int r = 0; r < 4; ++r) {
                    int row = bm*64 + wm*32 + mf*16 + r0 + r;
                    float v = acc[qn][mf][nf][r];
                    if (MODE == 0)      Cu[(size_t)row*ldc + col] = f2b(v + badd);
                    else if (MODE == 1) Cf[(size_t)row*ldc + col] = v;
                    else                Cu[(size_t)row*ldc + col] = f2b(v * scale);
                }
            }
}

// row softmax over 2048 bf16 z-scores, in place (z already scaled by 1/32)
__global__ __launch_bounds__(256)
void softmax_bf16(unsigned short* __restrict__ S) {
    int row = blockIdx.x;
    unsigned short* srow = S + (size_t)row * SEQ;
    int t = threadIdx.x;
    uint4 raw = ((const uint4*)srow)[t];
    const unsigned short* u = (const unsigned short*)&raw;
    float x[8];
    #pragma unroll
    for (int i = 0; i < 8; i++) x[i] = b2f(u[i]);
    float m = fmaxf(fmaxf(fmaxf(x[0],x[1]),fmaxf(x[2],x[3])),
                    fmaxf(fmaxf(x[4],x[5]),fmaxf(x[6],x[7])));
    #pragma unroll
    for (int off = 32; off; off >>= 1) m = fmaxf(m, __shfl_xor(m, off));
    __shared__ float redm[4], reds[4];
    int w = t >> 6;
    if ((t & 63) == 0) redm[w] = m;
    __syncthreads();
    m = fmaxf(fmaxf(redm[0], redm[1]), fmaxf(redm[2], redm[3]));
    float e[8]; float s = 0.f;
    #pragma unroll
    for (int i = 0; i < 8; i++) { e[i] = __expf(x[i] - m); s += e[i]; }
    #pragma unroll
    for (int off = 32; off; off >>= 1) s += __shfl_xor(s, off);
    if ((t & 63) == 0) reds[w] = s;
    __syncthreads();
    float inv = 1.0f / (reds[0]+reds[1]+reds[2]+reds[3]);
    union { unsigned short u[8]; uint4 v; } r;
    #pragma unroll
    for (int i = 0; i < 8; i++) r.u[i] = f2b(e[i] * inv);
    ((uint4*)srow)[t] = r.v;   // all cross-wave reads pre-barrier -> in-place safe
}

extern "C" void kernel_launch(void* const* d_in, const int* in_sizes, int n_in,
                              void* d_out, int out_size, void* d_ws, size_t ws_size,
                              hipStream_t stream)
{
    (void)in_sizes; (void)n_in; (void)out_size;
    const float* x  = (const float*)d_in[0];
    const float* Wq = (const float*)d_in[1];
    const float* bq = (const float*)d_in[2];
    const float* Wk = (const float*)d_in[3];
    const float* bk = (const float*)d_in[4];
    const float* Wv = (const float*)d_in[5];
    const float* bv = (const float*)d_in[6];
    float* out = (float*)d_out;

    unsigned short* qkv = (unsigned short*)d_ws;                    // [8192][3072]
    unsigned short* vt  = qkv + (size_t)MTOT*QKVN;                  // [4][1024][2048]
    float* biasc = (float*)(vt + (size_t)NB*DIM*SEQ);               // [3072]
    char* ovl = (char*)biasc + 65536;
    unsigned short* xb    = (unsigned short*)ovl;                   // [8192][1024]
    unsigned short* wqkvt = xb + (size_t)MTOT*DIM;                  // [3072][1024]
    unsigned short* scoresB = (unsigned short*)ovl;                 // [bpp][2048][2048] bf16

    size_t base = (size_t)MTOT*QKVN*2 + (size_t)NB*DIM*SEQ*2 + 65536;
    int bpp = 1;
    if (base + 4*(size_t)SEQ*SEQ*2 <= ws_size) bpp = 4;
    else if (base + 2*(size_t)SEQ*SEQ*2 <= ws_size) bpp = 2;

    cast_kernel<<<MTOT*DIM/8/256, 256, 0, stream>>>(x, xb, MTOT*DIM/8);
    transpose_cast3<<<dim3(256, 3), 256, 0, stream>>>(Wq, Wk, Wv, wqkvt);
    bias_concat<<<QKVN/256, 256, 0, stream>>>(bq, bk, bv, biasc);

    // fused QKV projection: [8192,1024] @ [3072,1024]^T, grid 128x12=1536 (3.0 rounds @ 2/CU)
    gemm4p<0><<<dim3((MTOT/64)*(QKVN/256)), 512, 0, stream>>>(
        xb, DIM, 0, wqkvt, DIM, 0, biasc, qkv, QKVN, 0, QKVN, DIM, 1.f);

    transpose_b16<<<dim3((SEQ/64)*(DIM/64), NB), 256, 0, stream>>>(
        qkv + 2*DIM, (size_t)SEQ*QKVN, QKVN, vt, (size_t)DIM*SEQ, SEQ, DIM/64);

    const float scl = 1.0f / 32.0f;   // 1/sqrt(1024), folded into scores GEMM write
    for (int p = 0; p < NB; p += bpp) {
        const unsigned short* qp = qkv + (size_t)p*SEQ*QKVN;
        // scores: z = (Q.K^T)/32 written bf16; grid 32x8 x bpp = 1024 (2.0 rounds)
        gemm4p<2><<<dim3((SEQ/64)*(SEQ/256), bpp), 512, 0, stream>>>(
            qp,       QKVN, (size_t)SEQ*QKVN,
            qp + DIM, QKVN, (size_t)SEQ*QKVN,
            nullptr, scoresB, SEQ, (size_t)SEQ*SEQ, SEQ, DIM, scl);
        softmax_bf16<<<bpp*SEQ, 256, 0, stream>>>(scoresB);
        // PV: out = P . V; grid 32x4 x bpp = 512 (1.0 round @ 2/CU)
        gemm4p<1><<<dim3((SEQ/64)*(DIM/256), bpp), 512, 0, stream>>>(
            scoresB, SEQ, (size_t)SEQ*SEQ,
            vt + (size_t)p*DIM*SEQ, SEQ, (size_t)DIM*SEQ,
            nullptr, out + (size_t)p*SEQ*DIM, DIM, (size_t)SEQ*DIM, DIM, SEQ, 1.f);
    }
}